// Round 6
// baseline (648.672 us; speedup 1.0000x reference)
//
#include <hip/hip_runtime.h>
#include <hip/hip_bf16.h>
#include <math.h>

// Sizes (fixed by the problem)
#define T_STEPS 1024
#define B_SZ 32
#define F_SZ 2048
#define H_SZ 64
#define G4 256      // 4*H
#define C_SZ 101

typedef __bf16 bf16x8 __attribute__((ext_vector_type(8)));
typedef unsigned short u16x8 __attribute__((ext_vector_type(8)));
typedef unsigned short u16x4 __attribute__((ext_vector_type(4)));
typedef float f32x4 __attribute__((ext_vector_type(4)));
typedef float f32x2 __attribute__((ext_vector_type(2)));

// Round-to-nearest-even fp32 -> bf16 split: f ~= hi + lo (each bf16).
__device__ __forceinline__ void split_bf16(float f, unsigned short& h,
                                           unsigned short& l) {
  unsigned u = __builtin_bit_cast(unsigned, f);
  unsigned rh = (u + 0x7FFFu + ((u >> 16) & 1u)) >> 16;
  h = (unsigned short)rh;
  float d = f - __builtin_bit_cast(float, rh << 16);
  unsigned ud = __builtin_bit_cast(unsigned, d);
  l = (unsigned short)((ud + 0x7FFFu + ((ud >> 16) & 1u)) >> 16);
}

// Packed dual-fp32 FMA (VOP3P). d.lo = fma(a.lo,b.lo,c.lo); same for .hi.
__device__ __forceinline__ f32x2 pk_fma(f32x2 a, f32x2 b, f32x2 c) {
  f32x2 d;
  asm("v_pk_fma_f32 %0, %1, %2, %3" : "=v"(d) : "v"(a), "v"(b), "v"(c));
  return d;
}
__device__ __forceinline__ f32x2 lo2(f32x4 v) {
  return __builtin_shufflevector(v, v, 0, 1);
}
__device__ __forceinline__ f32x2 hi2(f32x4 v) {
  return __builtin_shufflevector(v, v, 2, 3);
}

__device__ __forceinline__ float sigm_f(float x) {
  return __builtin_amdgcn_rcpf(1.f + __expf(-x));
}
__device__ __forceinline__ float tanh_f(float x) {
  return 2.f * __builtin_amdgcn_rcpf(1.f + __expf(-2.f * x)) - 1.f;
}

#define REP16(M) M(0) M(1) M(2) M(3) M(4) M(5) M(6) M(7) \
                 M(8) M(9) M(10) M(11) M(12) M(13) M(14) M(15)

// ---------------------------------------------------------------------------
// Phase 0: pre-split W_ih into bf16 hi/lo ONCE.
// ---------------------------------------------------------------------------
__global__ __launch_bounds__(256) void presplit_w(
    const float* __restrict__ W, unsigned short* __restrict__ hi,
    unsigned short* __restrict__ lo) {
  const int idx = (blockIdx.x * 256 + threadIdx.x) * 4;
  float4 v = *(const float4*)(W + idx);
  unsigned short h0, l0, h1, l1, h2, l2, h3, l3;
  split_bf16(v.x, h0, l0);
  split_bf16(v.y, h1, l1);
  split_bf16(v.z, h2, l2);
  split_bf16(v.w, h3, l3);
  *(u16x4*)(hi + idx) = u16x4{h0, h1, h2, h3};
  *(u16x4*)(lo + idx) = u16x4{l0, l1, l2, l3};
}

// ---------------------------------------------------------------------------
// Phase 1 (MFMA): xproj[t,b,j] = sum_f x[t,b,f]*W_ih[j,f] + b_ih[j] + b_hh[j]
// 128x256 tile, 8 waves, bf16-split 3-MFMA, BK=32; W pre-split from ws.
// ---------------------------------------------------------------------------
#define BM 128
#define BK 32
#define LDSP 40  // padded row stride in ushorts

__global__ __launch_bounds__(512) void xproj_mfma(
    const float* __restrict__ x, const unsigned short* __restrict__ Whi_g,
    const unsigned short* __restrict__ Wlo_g, const float* __restrict__ b_ih,
    const float* __restrict__ b_hh, float* __restrict__ xproj) {
  __shared__ alignas(16) unsigned short Xhi[BM][LDSP];
  __shared__ alignas(16) unsigned short Xlo[BM][LDSP];
  __shared__ alignas(16) unsigned short Whi[G4][LDSP];
  __shared__ alignas(16) unsigned short Wlo[G4][LDSP];

  const int tid = threadIdx.x;
  const int lane = tid & 63;
  const int wave = tid >> 6;  // 0..7
  const int wm = wave >> 2;   // 0..1 (M)
  const int wn = wave & 3;    // 0..3 (N)
  const size_t R0 = (size_t)blockIdx.x * BM;

  const int xr = tid >> 2;
  const int xs = (tid & 3) * 8;
  const int wr = tid >> 1;
  const int wsg = (tid & 1) * 16;

  const float* xbase = x + (R0 + xr) * (size_t)F_SZ + xs;
  const unsigned short* whb = Whi_g + (size_t)wr * F_SZ + wsg;
  const unsigned short* wlb = Wlo_g + (size_t)wr * F_SZ + wsg;

  float4 xa = *(const float4*)(xbase + 0);
  float4 xb = *(const float4*)(xbase + 4);
  u16x8 wh0 = *(const u16x8*)(whb + 0);
  u16x8 wh1 = *(const u16x8*)(whb + 8);
  u16x8 wl0 = *(const u16x8*)(wlb + 0);
  u16x8 wl1 = *(const u16x8*)(wlb + 8);

  f32x4 acc[4][4] = {};

  const int ar = lane & 15;
  const int ak = (lane >> 4) * 8;

  for (int kt = 0; kt < F_SZ; kt += BK) {
    {
      float xf[8] = {xa.x, xa.y, xa.z, xa.w, xb.x, xb.y, xb.z, xb.w};
      u16x8 xh, xl;
#pragma unroll
      for (int i = 0; i < 8; ++i) {
        unsigned short h, l;
        split_bf16(xf[i], h, l);
        xh[i] = h;
        xl[i] = l;
      }
      *(u16x8*)&Xhi[xr][xs] = xh;
      *(u16x8*)&Xlo[xr][xs] = xl;
      *(u16x8*)&Whi[wr][wsg] = wh0;
      *(u16x8*)&Whi[wr][wsg + 8] = wh1;
      *(u16x8*)&Wlo[wr][wsg] = wl0;
      *(u16x8*)&Wlo[wr][wsg + 8] = wl1;
    }
    __syncthreads();

    const int ktn = (kt + BK < F_SZ) ? kt + BK : kt;
    xa = *(const float4*)(xbase + ktn + 0);
    xb = *(const float4*)(xbase + ktn + 4);
    wh0 = *(const u16x8*)(whb + ktn + 0);
    wh1 = *(const u16x8*)(whb + ktn + 8);
    wl0 = *(const u16x8*)(wlb + ktn + 0);
    wl1 = *(const u16x8*)(wlb + ktn + 8);

    bf16x8 Ah[4], Al[4], Bh[4], Bl[4];
#pragma unroll
    for (int fm = 0; fm < 4; ++fm) {
      const int row = wm * 64 + fm * 16 + ar;
      Ah[fm] = __builtin_bit_cast(bf16x8, *(const u16x8*)&Xhi[row][ak]);
      Al[fm] = __builtin_bit_cast(bf16x8, *(const u16x8*)&Xlo[row][ak]);
    }
#pragma unroll
    for (int fn = 0; fn < 4; ++fn) {
      const int col = wn * 64 + fn * 16 + ar;
      Bh[fn] = __builtin_bit_cast(bf16x8, *(const u16x8*)&Whi[col][ak]);
      Bl[fn] = __builtin_bit_cast(bf16x8, *(const u16x8*)&Wlo[col][ak]);
    }
#pragma unroll
    for (int fm = 0; fm < 4; ++fm) {
#pragma unroll
      for (int fn = 0; fn < 4; ++fn) {
        acc[fm][fn] = __builtin_amdgcn_mfma_f32_16x16x32_bf16(
            Ah[fm], Bh[fn], acc[fm][fn], 0, 0, 0);
        acc[fm][fn] = __builtin_amdgcn_mfma_f32_16x16x32_bf16(
            Ah[fm], Bl[fn], acc[fm][fn], 0, 0, 0);
        acc[fm][fn] = __builtin_amdgcn_mfma_f32_16x16x32_bf16(
            Al[fm], Bh[fn], acc[fm][fn], 0, 0, 0);
      }
    }
    __syncthreads();
  }

  const int cr = (lane >> 4) * 4;
  const int cc = lane & 15;
#pragma unroll
  for (int fn = 0; fn < 4; ++fn) {
    const int gj = wn * 64 + fn * 16 + cc;
    const float bias = b_ih[gj] + b_hh[gj];
#pragma unroll
    for (int fm = 0; fm < 4; ++fm) {
      const size_t gr = R0 + wm * 64 + fm * 16 + cr;
#pragma unroll
      for (int r = 0; r < 4; ++r) {
        xproj[(gr + r) * G4 + gj] = acc[fm][fn][r] + bias;
      }
    }
  }
}

// ---------------------------------------------------------------------------
// Phase 2: LSTM scan. 32 blocks x 256 threads (4 waves; one GATE ROW per
// thread: g=j>>6, u=j&63).
//  - W row PINNED in VGPRs via asm volatile global_load_dwordx4 (cannot be
//    sunk/rematerialized — R4/R5 showed the compiler re-loads plain loads:
//    VGPR_Count stayed 48).
//  - ONE barrier/step: act double-buffered by t&1 (no WAR), h in a PER-WAVE
//    private LDS buffer (each wave computes full h redundantly; same-wave
//    lgkmcnt ordering, no cross-wave dependence).
//  - Barrier = raw "s_waitcnt lgkmcnt(0); s_barrier" (NO vmcnt drain, so the
//    2-deep x-prefetch stays in flight across steps).
// ---------------------------------------------------------------------------
__global__ __launch_bounds__(256, 1) void lstm_scan4(
    const float* __restrict__ xproj, const float* __restrict__ W_hh,
    float* __restrict__ hT) {
  const int b = blockIdx.x;   // 0..31
  const int j = threadIdx.x;  // 0..255: gate g=j>>6, unit u=j&63
  const int u = j & 63;
  const int g = j >> 6;

  __shared__ alignas(16) float h_own[4][H_SZ];   // per-wave private h
  __shared__ alignas(16) float act_lds[2][G4];   // [parity][u*4+g]

  // --- pin W_hh row j into 16 VGPR quads (asm volatile: not sinkable) ---
  const float* wp = W_hh + (size_t)j * H_SZ;
#define PINW(i)                                             \
  f32x4 w_##i;                                              \
  {                                                         \
    const float* ap_##i = wp + 4 * (i);                     \
    asm volatile("global_load_dwordx4 %0, %1, off"          \
                 : "=v"(w_##i) : "v"(ap_##i));              \
  }
  REP16(PINW)
#undef PINW
  asm volatile("s_waitcnt vmcnt(0)" ::: "memory");

  h_own[g][u] = 0.f;  // own wave's buffer; same-wave visibility
  float c = 0.f;      // replica of c[u] (identical ops -> identical bits)
  float hval = 0.f;

  const float* xpb = xproj + (size_t)b * G4 + j;  // stride per t: B*G4
  // 2-deep x prefetch (HBM latency ~900cyc > 1 step)
  float xv = xpb[0];
  float xn1 = xpb[(size_t)1 * (B_SZ * G4)];

  for (int t = 0; t < T_STEPS; ++t) {
    // issue prefetch for t+2 (consumed 2 iterations later)
    const int tpre = (t + 2 < T_STEPS) ? t + 2 : t;
    const float xn2 = xpb[(size_t)tpre * (B_SZ * G4)];

    // h broadcast from OWN wave's buffer (uniform addr -> LDS broadcast)
#define LH(i) const f32x4 h_##i = *(const f32x4*)&h_own[g][4 * (i)];
    REP16(LH)
#undef LH

    // dot(h, w): 32 pk_fma in 4 independent chains
    f32x2 aA = {0.f, 0.f}, aB = {0.f, 0.f};
    f32x2 aC = {0.f, 0.f}, aD = {0.f, 0.f};
#define ACC_AB(i)                              \
    aA = pk_fma(lo2(h_##i), lo2(w_##i), aA);   \
    aB = pk_fma(hi2(h_##i), hi2(w_##i), aB);
#define ACC_CD(i)                              \
    aC = pk_fma(lo2(h_##i), lo2(w_##i), aC);   \
    aD = pk_fma(hi2(h_##i), hi2(w_##i), aD);
    ACC_AB(0) ACC_AB(1) ACC_AB(2) ACC_AB(3)
    ACC_AB(4) ACC_AB(5) ACC_AB(6) ACC_AB(7)
    ACC_CD(8) ACC_CD(9) ACC_CD(10) ACC_CD(11)
    ACC_CD(12) ACC_CD(13) ACC_CD(14) ACC_CD(15)
#undef ACC_AB
#undef ACC_CD
    const float pre =
        xv + ((aA[0] + aA[1]) + (aB[0] + aB[1])) +
             ((aC[0] + aC[1]) + (aD[0] + aD[1]));

    // activation: wave-uniform branch (wave 2 = tanh, others = sigmoid)
    const float a = (g == 2) ? tanh_f(pre) : sigm_f(pre);
    const int p = t & 1;
    act_lds[p][u * 4 + g] = a;

    // single barrier per step; drains LDS only (keeps vm prefetch in flight)
    asm volatile("s_waitcnt lgkmcnt(0)\n\ts_barrier" ::: "memory");

    // all 4 gates for unit u in one b128
    const f32x4 av = *(const f32x4*)&act_lds[p][u * 4];
    c = av[1] * c + av[0] * av[2];
    hval = av[3] * tanh_f(c);
    h_own[g][u] = hval;  // own-wave write; read next step via lgkmcnt order

    xv = xn1;
    xn1 = xn2;
  }

  if (g == 0) hT[b * H_SZ + u] = hval;
}

// ---------------------------------------------------------------------------
// Phase 3: out[b][c] = sum_k hT[b][k] * W_lin[c][k] + b_lin[c]
// ---------------------------------------------------------------------------
__global__ __launch_bounds__(128) void final_linear_kernel(
    const float* __restrict__ hT, const float* __restrict__ W_lin,
    const float* __restrict__ b_lin, float* __restrict__ out) {
  const int b = blockIdx.x;
  const int cc = threadIdx.x;

  __shared__ float h_l[H_SZ];
  if (threadIdx.x < H_SZ) h_l[threadIdx.x] = hT[b * H_SZ + threadIdx.x];
  __syncthreads();

  if (cc < C_SZ) {
    float acc = b_lin[cc];
    const float* wr = W_lin + (size_t)cc * H_SZ;
#pragma unroll
    for (int k = 0; k < H_SZ; ++k) acc += h_l[k] * wr[k];
    out[b * C_SZ + cc] = acc;
  }
}

// ---------------------------------------------------------------------------
extern "C" void kernel_launch(void* const* d_in, const int* in_sizes, int n_in,
                              void* d_out, int out_size, void* d_ws,
                              size_t ws_size, hipStream_t stream) {
  const float* x = (const float*)d_in[0];      // [T,B,F]
  const float* W_ih = (const float*)d_in[1];   // [4H,F]
  const float* W_hh = (const float*)d_in[2];   // [4H,H]
  const float* b_ih = (const float*)d_in[3];   // [4H]
  const float* b_hh = (const float*)d_in[4];   // [4H]
  const float* W_lin = (const float*)d_in[5];  // [C,H]
  const float* b_lin = (const float*)d_in[6];  // [C]
  float* out = (float*)d_out;                  // [B,C]

  // ws layout: xproj 32MB | hT 8KB | Whi 1MB | Wlo 1MB
  const size_t XP_BYTES = (size_t)T_STEPS * B_SZ * G4 * sizeof(float);
  float* xproj = (float*)d_ws;
  float* hT = (float*)((char*)d_ws + XP_BYTES);
  unsigned short* Whi_g = (unsigned short*)((char*)d_ws + XP_BYTES + 8192);
  unsigned short* Wlo_g = Whi_g + (size_t)G4 * F_SZ;

  presplit_w<<<512, 256, 0, stream>>>(W_ih, Whi_g, Wlo_g);
  xproj_mfma<<<(T_STEPS * B_SZ) / BM, 512, 0, stream>>>(x, Whi_g, Wlo_g, b_ih,
                                                        b_hh, xproj);
  lstm_scan4<<<B_SZ, 256, 0, stream>>>(xproj, W_hh, hT);
  final_linear_kernel<<<B_SZ, 128, 0, stream>>>(hT, W_lin, b_lin, out);
}

// Round 7
// 588.835 us; speedup vs baseline: 1.1016x; 1.1016x over previous
//
#include <hip/hip_runtime.h>
#include <hip/hip_bf16.h>
#include <math.h>

// Sizes (fixed by the problem)
#define T_STEPS 1024
#define B_SZ 32
#define F_SZ 2048
#define H_SZ 64
#define G4 256      // 4*H
#define C_SZ 101

typedef __bf16 bf16x8 __attribute__((ext_vector_type(8)));
typedef unsigned short u16x8 __attribute__((ext_vector_type(8)));
typedef unsigned short u16x4 __attribute__((ext_vector_type(4)));
typedef float f32x4 __attribute__((ext_vector_type(4)));
typedef float f32x2 __attribute__((ext_vector_type(2)));

// Round-to-nearest-even fp32 -> bf16 split: f ~= hi + lo (each bf16).
__device__ __forceinline__ void split_bf16(float f, unsigned short& h,
                                           unsigned short& l) {
  unsigned u = __builtin_bit_cast(unsigned, f);
  unsigned rh = (u + 0x7FFFu + ((u >> 16) & 1u)) >> 16;
  h = (unsigned short)rh;
  float d = f - __builtin_bit_cast(float, rh << 16);
  unsigned ud = __builtin_bit_cast(unsigned, d);
  l = (unsigned short)((ud + 0x7FFFu + ((ud >> 16) & 1u)) >> 16);
}

// Packed dual-fp32 FMA (VOP3P). d.lo = fma(a.lo,b.lo,c.lo); same for .hi.
__device__ __forceinline__ f32x2 pk_fma(f32x2 a, f32x2 b, f32x2 c) {
  f32x2 d;
  asm("v_pk_fma_f32 %0, %1, %2, %3" : "=v"(d) : "v"(a), "v"(b), "v"(c));
  return d;
}
__device__ __forceinline__ f32x2 lo2(f32x4 v) {
  return __builtin_shufflevector(v, v, 0, 1);
}
__device__ __forceinline__ f32x2 hi2(f32x4 v) {
  return __builtin_shufflevector(v, v, 2, 3);
}

__device__ __forceinline__ float sigm_f(float x) {
  return __builtin_amdgcn_rcpf(1.f + __expf(-x));
}
__device__ __forceinline__ float tanh_f(float x) {
  return 2.f * __builtin_amdgcn_rcpf(1.f + __expf(-2.f * x)) - 1.f;
}

#define REP16(M) M(0) M(1) M(2) M(3) M(4) M(5) M(6) M(7) \
                 M(8) M(9) M(10) M(11) M(12) M(13) M(14) M(15)

// ---------------------------------------------------------------------------
// Phase 0: pre-split W_ih into bf16 hi/lo ONCE.
// ---------------------------------------------------------------------------
__global__ __launch_bounds__(256) void presplit_w(
    const float* __restrict__ W, unsigned short* __restrict__ hi,
    unsigned short* __restrict__ lo) {
  const int idx = (blockIdx.x * 256 + threadIdx.x) * 4;
  float4 v = *(const float4*)(W + idx);
  unsigned short h0, l0, h1, l1, h2, l2, h3, l3;
  split_bf16(v.x, h0, l0);
  split_bf16(v.y, h1, l1);
  split_bf16(v.z, h2, l2);
  split_bf16(v.w, h3, l3);
  *(u16x4*)(hi + idx) = u16x4{h0, h1, h2, h3};
  *(u16x4*)(lo + idx) = u16x4{l0, l1, l2, l3};
}

// ---------------------------------------------------------------------------
// Phase 1 (MFMA): xproj[t,b,j] = sum_f x[t,b,f]*W_ih[j,f] + b_ih[j] + b_hh[j]
// 128x256 tile, 8 waves, bf16-split 3-MFMA, BK=32; W pre-split from ws.
// ---------------------------------------------------------------------------
#define BM 128
#define BK 32
#define LDSP 40  // padded row stride in ushorts

__global__ __launch_bounds__(512) void xproj_mfma(
    const float* __restrict__ x, const unsigned short* __restrict__ Whi_g,
    const unsigned short* __restrict__ Wlo_g, const float* __restrict__ b_ih,
    const float* __restrict__ b_hh, float* __restrict__ xproj) {
  __shared__ alignas(16) unsigned short Xhi[BM][LDSP];
  __shared__ alignas(16) unsigned short Xlo[BM][LDSP];
  __shared__ alignas(16) unsigned short Whi[G4][LDSP];
  __shared__ alignas(16) unsigned short Wlo[G4][LDSP];

  const int tid = threadIdx.x;
  const int lane = tid & 63;
  const int wave = tid >> 6;  // 0..7
  const int wm = wave >> 2;   // 0..1 (M)
  const int wn = wave & 3;    // 0..3 (N)
  const size_t R0 = (size_t)blockIdx.x * BM;

  const int xr = tid >> 2;
  const int xs = (tid & 3) * 8;
  const int wr = tid >> 1;
  const int wsg = (tid & 1) * 16;

  const float* xbase = x + (R0 + xr) * (size_t)F_SZ + xs;
  const unsigned short* whb = Whi_g + (size_t)wr * F_SZ + wsg;
  const unsigned short* wlb = Wlo_g + (size_t)wr * F_SZ + wsg;

  float4 xa = *(const float4*)(xbase + 0);
  float4 xb = *(const float4*)(xbase + 4);
  u16x8 wh0 = *(const u16x8*)(whb + 0);
  u16x8 wh1 = *(const u16x8*)(whb + 8);
  u16x8 wl0 = *(const u16x8*)(wlb + 0);
  u16x8 wl1 = *(const u16x8*)(wlb + 8);

  f32x4 acc[4][4] = {};

  const int ar = lane & 15;
  const int ak = (lane >> 4) * 8;

  for (int kt = 0; kt < F_SZ; kt += BK) {
    {
      float xf[8] = {xa.x, xa.y, xa.z, xa.w, xb.x, xb.y, xb.z, xb.w};
      u16x8 xh, xl;
#pragma unroll
      for (int i = 0; i < 8; ++i) {
        unsigned short h, l;
        split_bf16(xf[i], h, l);
        xh[i] = h;
        xl[i] = l;
      }
      *(u16x8*)&Xhi[xr][xs] = xh;
      *(u16x8*)&Xlo[xr][xs] = xl;
      *(u16x8*)&Whi[wr][wsg] = wh0;
      *(u16x8*)&Whi[wr][wsg + 8] = wh1;
      *(u16x8*)&Wlo[wr][wsg] = wl0;
      *(u16x8*)&Wlo[wr][wsg + 8] = wl1;
    }
    __syncthreads();

    const int ktn = (kt + BK < F_SZ) ? kt + BK : kt;
    xa = *(const float4*)(xbase + ktn + 0);
    xb = *(const float4*)(xbase + ktn + 4);
    wh0 = *(const u16x8*)(whb + ktn + 0);
    wh1 = *(const u16x8*)(whb + ktn + 8);
    wl0 = *(const u16x8*)(wlb + ktn + 0);
    wl1 = *(const u16x8*)(wlb + ktn + 8);

    bf16x8 Ah[4], Al[4], Bh[4], Bl[4];
#pragma unroll
    for (int fm = 0; fm < 4; ++fm) {
      const int row = wm * 64 + fm * 16 + ar;
      Ah[fm] = __builtin_bit_cast(bf16x8, *(const u16x8*)&Xhi[row][ak]);
      Al[fm] = __builtin_bit_cast(bf16x8, *(const u16x8*)&Xlo[row][ak]);
    }
#pragma unroll
    for (int fn = 0; fn < 4; ++fn) {
      const int col = wn * 64 + fn * 16 + ar;
      Bh[fn] = __builtin_bit_cast(bf16x8, *(const u16x8*)&Whi[col][ak]);
      Bl[fn] = __builtin_bit_cast(bf16x8, *(const u16x8*)&Wlo[col][ak]);
    }
#pragma unroll
    for (int fm = 0; fm < 4; ++fm) {
#pragma unroll
      for (int fn = 0; fn < 4; ++fn) {
        acc[fm][fn] = __builtin_amdgcn_mfma_f32_16x16x32_bf16(
            Ah[fm], Bh[fn], acc[fm][fn], 0, 0, 0);
        acc[fm][fn] = __builtin_amdgcn_mfma_f32_16x16x32_bf16(
            Ah[fm], Bl[fn], acc[fm][fn], 0, 0, 0);
        acc[fm][fn] = __builtin_amdgcn_mfma_f32_16x16x32_bf16(
            Al[fm], Bh[fn], acc[fm][fn], 0, 0, 0);
      }
    }
    __syncthreads();
  }

  const int cr = (lane >> 4) * 4;
  const int cc = lane & 15;
#pragma unroll
  for (int fn = 0; fn < 4; ++fn) {
    const int gj = wn * 64 + fn * 16 + cc;
    const float bias = b_ih[gj] + b_hh[gj];
#pragma unroll
    for (int fm = 0; fm < 4; ++fm) {
      const size_t gr = R0 + wm * 64 + fm * 16 + cr;
#pragma unroll
      for (int r = 0; r < 4; ++r) {
        xproj[(gr + r) * G4 + gj] = acc[fm][fn][r] + bias;
      }
    }
  }
}

// ---------------------------------------------------------------------------
// Phase 2: LSTM scan. 32 blocks x 256 threads (4 waves; one GATE ROW per
// thread: g=j>>6, u=j&63).
//  - amdgpu_waves_per_eu(1,1): occupancy target = 1 wave/EU, so the scheduler
//    and RA have NO incentive to squeeze VGPR pressure under 64 — this is the
//    fix for R4/R5/R6 where W kept getting sunk/spilled (VGPR_Count 48).
//  - W row pinned via asm volatile global_load_dwordx4 (not sinkable).
//  - ONE barrier/step (lgkm-only, no vmcnt drain): act double-buffered by
//    t&1 in GATE-MAJOR layout (conflict-free: R5 had 0 conflicts; R6's
//    unit-major was 8-way, 786K); h in per-wave private LDS (redundant
//    update per wave, same-wave lgkmcnt ordering).
//  - 2-deep x-prefetch stays in flight across the barrier.
// ---------------------------------------------------------------------------
__global__ __attribute__((amdgpu_flat_work_group_size(256, 256)))
__attribute__((amdgpu_waves_per_eu(1, 1))) void lstm_scan4(
    const float* __restrict__ xproj, const float* __restrict__ W_hh,
    float* __restrict__ hT) {
  const int b = blockIdx.x;   // 0..31
  const int j = threadIdx.x;  // 0..255: gate g=j>>6, unit u=j&63
  const int u = j & 63;
  const int g = j >> 6;

  __shared__ alignas(16) float h_own[4][H_SZ];   // per-wave private h
  __shared__ alignas(16) float act_lds[2][G4];   // [parity][g*64+u] gate-major

  // --- pin W_hh row j into 16 VGPR quads (asm volatile: not sinkable) ---
  const float* wp = W_hh + (size_t)j * H_SZ;
#define PINW(i)                                             \
  f32x4 w_##i;                                              \
  {                                                         \
    const float* ap_##i = wp + 4 * (i);                     \
    asm volatile("global_load_dwordx4 %0, %1, off"          \
                 : "=v"(w_##i) : "v"(ap_##i));              \
  }
  REP16(PINW)
#undef PINW
  asm volatile("s_waitcnt vmcnt(0)" ::: "memory");

  h_own[g][u] = 0.f;  // own wave's buffer; same-wave visibility
  float c = 0.f;      // replica of c[u] (identical ops -> identical bits)
  float hval = 0.f;

  const float* xpb = xproj + (size_t)b * G4 + j;  // stride per t: B*G4
  // 2-deep x prefetch (HBM latency ~900cyc > 1 step)
  float xv = xpb[0];
  float xn1 = xpb[(size_t)1 * (B_SZ * G4)];

  for (int t = 0; t < T_STEPS; ++t) {
    // issue prefetch for t+2 (consumed 2 iterations later)
    const int tpre = (t + 2 < T_STEPS) ? t + 2 : t;
    const float xn2 = xpb[(size_t)tpre * (B_SZ * G4)];

    // h broadcast from OWN wave's buffer (uniform addr -> LDS broadcast)
#define LH(i) const f32x4 h_##i = *(const f32x4*)&h_own[g][4 * (i)];
    REP16(LH)
#undef LH

    // dot(h, w): 32 pk_fma in 4 independent chains
    f32x2 aA = {0.f, 0.f}, aB = {0.f, 0.f};
    f32x2 aC = {0.f, 0.f}, aD = {0.f, 0.f};
#define ACC_AB(i)                              \
    aA = pk_fma(lo2(h_##i), lo2(w_##i), aA);   \
    aB = pk_fma(hi2(h_##i), hi2(w_##i), aB);
#define ACC_CD(i)                              \
    aC = pk_fma(lo2(h_##i), lo2(w_##i), aC);   \
    aD = pk_fma(hi2(h_##i), hi2(w_##i), aD);
    ACC_AB(0) ACC_AB(1) ACC_AB(2) ACC_AB(3)
    ACC_AB(4) ACC_AB(5) ACC_AB(6) ACC_AB(7)
    ACC_CD(8) ACC_CD(9) ACC_CD(10) ACC_CD(11)
    ACC_CD(12) ACC_CD(13) ACC_CD(14) ACC_CD(15)
#undef ACC_AB
#undef ACC_CD
    const float pre =
        xv + ((aA[0] + aA[1]) + (aB[0] + aB[1])) +
             ((aC[0] + aC[1]) + (aD[0] + aD[1]));

    // activation: wave-uniform branch (wave 2 = tanh, others = sigmoid)
    const float a = (g == 2) ? tanh_f(pre) : sigm_f(pre);
    const int p = t & 1;
    act_lds[p][j] = a;  // gate-major: stride-1 within wave, conflict-free

    // single barrier per step; drains LDS only (keeps vm prefetch in flight)
    asm volatile("s_waitcnt lgkmcnt(0)\n\ts_barrier" ::: "memory");

    // 4 stride-1 ds_read_b32, each conflict-free
    const float ai = act_lds[p][u];
    const float af = act_lds[p][64 + u];
    const float ag = act_lds[p][128 + u];
    const float ao = act_lds[p][192 + u];
    c = af * c + ai * ag;
    hval = ao * tanh_f(c);
    h_own[g][u] = hval;  // own-wave write; read next step via lgkmcnt order

    xv = xn1;
    xn1 = xn2;
  }

  if (g == 0) hT[b * H_SZ + u] = hval;
}

// ---------------------------------------------------------------------------
// Phase 3: out[b][c] = sum_k hT[b][k] * W_lin[c][k] + b_lin[c]
// ---------------------------------------------------------------------------
__global__ __launch_bounds__(128) void final_linear_kernel(
    const float* __restrict__ hT, const float* __restrict__ W_lin,
    const float* __restrict__ b_lin, float* __restrict__ out) {
  const int b = blockIdx.x;
  const int cc = threadIdx.x;

  __shared__ float h_l[H_SZ];
  if (threadIdx.x < H_SZ) h_l[threadIdx.x] = hT[b * H_SZ + threadIdx.x];
  __syncthreads();

  if (cc < C_SZ) {
    float acc = b_lin[cc];
    const float* wr = W_lin + (size_t)cc * H_SZ;
#pragma unroll
    for (int k = 0; k < H_SZ; ++k) acc += h_l[k] * wr[k];
    out[b * C_SZ + cc] = acc;
  }
}

// ---------------------------------------------------------------------------
extern "C" void kernel_launch(void* const* d_in, const int* in_sizes, int n_in,
                              void* d_out, int out_size, void* d_ws,
                              size_t ws_size, hipStream_t stream) {
  const float* x = (const float*)d_in[0];      // [T,B,F]
  const float* W_ih = (const float*)d_in[1];   // [4H,F]
  const float* W_hh = (const float*)d_in[2];   // [4H,H]
  const float* b_ih = (const float*)d_in[3];   // [4H]
  const float* b_hh = (const float*)d_in[4];   // [4H]
  const float* W_lin = (const float*)d_in[5];  // [C,H]
  const float* b_lin = (const float*)d_in[6];  // [C]
  float* out = (float*)d_out;                  // [B,C]

  // ws layout: xproj 32MB | hT 8KB | Whi 1MB | Wlo 1MB
  const size_t XP_BYTES = (size_t)T_STEPS * B_SZ * G4 * sizeof(float);
  float* xproj = (float*)d_ws;
  float* hT = (float*)((char*)d_ws + XP_BYTES);
  unsigned short* Whi_g = (unsigned short*)((char*)d_ws + XP_BYTES + 8192);
  unsigned short* Wlo_g = Whi_g + (size_t)G4 * F_SZ;

  presplit_w<<<512, 256, 0, stream>>>(W_ih, Whi_g, Wlo_g);
  xproj_mfma<<<(T_STEPS * B_SZ) / BM, 512, 0, stream>>>(x, Whi_g, Wlo_g, b_ih,
                                                        b_hh, xproj);
  lstm_scan4<<<B_SZ, 256, 0, stream>>>(xproj, W_hh, hT);
  final_linear_kernel<<<B_SZ, 128, 0, stream>>>(hT, W_lin, b_lin, out);
}